// Round 3
// baseline (1256.933 us; speedup 1.0000x reference)
//
#include <hip/hip_runtime.h>
#include <hip/hip_cooperative_groups.h>

namespace cg = cooperative_groups;

constexpr int IMW  = 96;
constexpr int NPIX = 9216;
constexpr int TB   = 256;              // threads per block
constexpr int JT   = 2;                // j's per thread in bilat
constexpr int JB   = NPIX/(TB*JT);     // 18 j-blocks
constexpr int SI   = 192;              // i's per segment (2 image rows)
constexpr int NSEG = NPIX/SI;          // 48 segments
constexpr int NBIL = JB*NSEG;          // 864 bilat blocks
constexpr int NUPD = NPIX/TB;          // 36 update / gaussH blocks
constexpr int GRID = NBIL + NUPD;      // 900
constexpr int NIT  = 5;

constexpr float LCLIP = 18.420681f;               // -log(1e-8)
constexpr float LOG2E = 1.4426950408889634f;
constexpr float C1 = -LOG2E/18.0f;                // gaussian (sxy=3), base-2
constexpr float C2 = -LOG2E/5000.0f;              // bilateral spatial (sxy=50)
constexpr float C3 = -LOG2E/400.0f;               // bilateral feature (2*df^2/(2*20^2))

// ---------------- device phase functions ----------------

__device__ __forceinline__ void do_init(int g, const int* __restrict__ mask,
                                        float* __restrict__ du, float* __restrict__ q,
                                        float* __restrict__ S){
    if (g < NPIX){
        float d = (mask[g]==0) ? LCLIP : -LCLIP;
        du[g] = d;
        q[g]  = 1.0f/(1.0f + __expf(d));
    }
    if (g < IMW){
        float t = (float)g, acc = 0.f;
        for (int xp = 0; xp < IMW; ++xp){
            float dd = t - (float)xp;
            acc += exp2f(C1*dd*dd);
        }
        S[g] = acc;       // 1D gaussian row sum (for Ksum)
    }
}

template<bool KSUM>
__device__ __forceinline__ void bilat_seg(const float4* st, int rowbase,
                                          float xj0, float yj0, float mj0, float b0,
                                          float xj1, float yj1, float mj1, float b1,
                                          float& acc0, float& acc1,
                                          float& ak0, float& ak1){
    for (int r = 0; r < 2; ++r){
        float ry  = (float)(rowbase + r);
        float dy0 = ry - yj0, dy1 = ry - yj1;
        float asp0 = fmaf(dy0, dy0, xj0*xj0)*C2 + b0;   // C2*(xj^2+dy^2)+C3*fj^2
        float asp1 = fmaf(dy1, dy1, xj1*xj1)*C2 + b1;
        float d0 = C2*(1.0f - 2.0f*xj0);
        float d1 = C2*(1.0f - 2.0f*xj1);
        #pragma unroll 8
        for (int x = 0; x < IMW; ++x){
            float4 s = st[r*IMW + x];                    // wave-uniform broadcast
            float t0 = fmaf(s.x, mj0, s.y);              // fi*mj + C3*fi^2
            float t1 = fmaf(s.x, mj1, s.y);
            float e0 = exp2f(asp0 + t0);
            float e1 = exp2f(asp1 + t1);
            acc0 = fmaf(s.z, e0, acc0);
            acc1 = fmaf(s.z, e1, acc1);
            if (KSUM){ ak0 += e0; ak1 += e1; }
            asp0 += d0; asp1 += d1;
            d0 += 2.0f*C2; d1 += 2.0f*C2;
        }
    }
}

__device__ __forceinline__ void do_phaseA(int bid, int tid, int iter, float4* st,
                                          const float* __restrict__ img,
                                          const float* __restrict__ q,
                                          float* __restrict__ gH,
                                          float* __restrict__ pmsg,
                                          float* __restrict__ pksum){
    if (bid < NBIL){
        const int jb  = bid / NSEG;
        const int seg = bid % NSEG;
        if (tid < SI){
            int i = seg*SI + tid;
            float fi = img[i];
            st[tid] = make_float4(fi, C3*fi*fi, q[i], 0.f);
        }
        const int j0 = jb*(TB*JT) + tid;
        const int j1 = j0 + TB;
        const float xj0 = (float)(j0 % IMW), yj0 = (float)(j0 / IMW);
        const float xj1 = (float)(j1 % IMW), yj1 = (float)(j1 / IMW);
        const float f0 = img[j0], f1 = img[j1];
        const float mj0 = -2.0f*C3*f0, mj1 = -2.0f*C3*f1;
        const float b0 = C3*f0*f0, b1 = C3*f1*f1;
        __syncthreads();
        float acc0=0.f, acc1=0.f, ak0=0.f, ak1=0.f;
        if (iter == 0)
            bilat_seg<true >(st, seg*2, xj0,yj0,mj0,b0, xj1,yj1,mj1,b1, acc0,acc1,ak0,ak1);
        else
            bilat_seg<false>(st, seg*2, xj0,yj0,mj0,b0, xj1,yj1,mj1,b1, acc0,acc1,ak0,ak1);
        pmsg[seg*NPIX + j0] = acc0;
        pmsg[seg*NPIX + j1] = acc1;
        if (iter == 0){
            pksum[seg*NPIX + j0] = ak0;
            pksum[seg*NPIX + j1] = ak1;
        }
    } else {
        // separable gaussian, horizontal pass
        int j  = (bid - NBIL)*TB + tid;
        int xj = j % IMW, yj = j / IMW;
        const float* row = q + yj*IMW;
        float asp = C1*(float)(xj*xj);
        float d   = C1*(1.0f - 2.0f*(float)xj);
        float acc = 0.f;
        #pragma unroll 8
        for (int xp = 0; xp < IMW; ++xp){
            acc = fmaf(row[xp], exp2f(asp), acc);
            asp += d; d += 2.0f*C1;
        }
        gH[j] = acc;
    }
}

__device__ __forceinline__ void do_phaseB(int bid, int tid, int iter,
                                          const float* __restrict__ gH,
                                          const float* __restrict__ pmsg,
                                          const float* __restrict__ pksum,
                                          const float* __restrict__ S,
                                          const float* __restrict__ du,
                                          float* __restrict__ ksum,
                                          float* __restrict__ q,
                                          float* __restrict__ out){
    if (bid >= NUPD) return;
    int j  = bid*TB + tid;
    int xj = j % IMW, yj = j / IMW;
    // vertical gaussian pass, per j
    float asp = C1*(float)(yj*yj);
    float d   = C1*(1.0f - 2.0f*(float)yj);
    float gv  = 0.f;
    #pragma unroll 8
    for (int yp = 0; yp < IMW; ++yp){
        gv = fmaf(gH[yp*IMW + xj], exp2f(asp), gv);
        asp += d; d += 2.0f*C1;
    }
    // reduce bilateral partials (fixed order -> deterministic)
    float B = 0.f;
    #pragma unroll
    for (int s = 0; s < NSEG; ++s) B += pmsg[s*NPIX + j];
    float K;
    if (iter == 0){
        float Bk = 0.f;
        #pragma unroll
        for (int s = 0; s < NSEG; ++s) Bk += pksum[s*NPIX + j];
        K = 3.0f*S[xj]*S[yj] + 10.0f*Bk - 13.0f;    // remove diagonal (3+10)
        ksum[j] = K;
    } else {
        K = ksum[j];
    }
    float m = 3.0f*gv + 10.0f*B - 13.0f*q[j];        // remove diagonal q_j*13
    float delta = du[j] + K - 2.0f*m;                // logit(1)-logit(0)
    if (iter == NIT-1){
        out[j] = (delta > 0.f) ? 1.0f : 0.0f;
    } else {
        q[j] = 1.0f/(1.0f + __expf(delta));
    }
}

// ---------------- cooperative single-launch kernel ----------------

__global__ __launch_bounds__(TB, 4) void crf_all(
        const float* __restrict__ img, const int* __restrict__ mask,
        float* __restrict__ out,
        float* __restrict__ q, float* __restrict__ du, float* __restrict__ ksum,
        float* __restrict__ gH, float* __restrict__ S,
        float* __restrict__ pmsg, float* __restrict__ pksum){
    cg::grid_group grid = cg::this_grid();
    __shared__ float4 st[SI];
    const int bid = blockIdx.x, tid = threadIdx.x;

    do_init(bid*TB + tid, mask, du, q, S);
    grid.sync();

    for (int iter = 0; iter < NIT; ++iter){
        do_phaseA(bid, tid, iter, st, img, q, gH, pmsg, pksum);
        grid.sync();
        do_phaseB(bid, tid, iter, gH, pmsg, pksum, S, du, ksum, q, out);
        grid.sync();
    }
}

// ---------------- discrete-launch fallback kernels ----------------

__global__ __launch_bounds__(TB) void k_init(const int* __restrict__ mask,
                                             float* __restrict__ du, float* __restrict__ q,
                                             float* __restrict__ S){
    do_init(blockIdx.x*TB + threadIdx.x, mask, du, q, S);
}

__global__ __launch_bounds__(TB) void k_phaseA(int iter, const float* __restrict__ img,
                                               const float* __restrict__ q,
                                               float* __restrict__ gH,
                                               float* __restrict__ pmsg,
                                               float* __restrict__ pksum){
    __shared__ float4 st[SI];
    do_phaseA(blockIdx.x, threadIdx.x, iter, st, img, q, gH, pmsg, pksum);
}

__global__ __launch_bounds__(TB) void k_phaseB(int iter,
                                               const float* __restrict__ gH,
                                               const float* __restrict__ pmsg,
                                               const float* __restrict__ pksum,
                                               const float* __restrict__ S,
                                               const float* __restrict__ du,
                                               float* __restrict__ ksum,
                                               float* __restrict__ q,
                                               float* __restrict__ out){
    do_phaseB(blockIdx.x, threadIdx.x, iter, gH, pmsg, pksum, S, du, ksum, q, out);
}

// ---------------- host launcher ----------------

extern "C" void kernel_launch(void* const* d_in, const int* in_sizes, int n_in,
                              void* d_out, int out_size, void* d_ws, size_t ws_size,
                              hipStream_t stream){
    const float* img  = (const float*)d_in[0];
    const int*   mask = (const int*)d_in[1];
    float* out = (float*)d_out;
    float* ws  = (float*)d_ws;

    float* q     = ws;
    float* du    = q    + NPIX;
    float* ksum  = du   + NPIX;
    float* gH    = ksum + NPIX;
    float* S     = gH   + NPIX;          // 96, pad to 128
    float* pmsg  = S    + 128;
    float* pksum = pmsg + (size_t)NSEG*NPIX;

    void* args[] = { (void*)&img, (void*)&mask, (void*)&out, (void*)&q, (void*)&du,
                     (void*)&ksum, (void*)&gH, (void*)&S, (void*)&pmsg, (void*)&pksum };
    hipError_t e = hipLaunchCooperativeKernel((const void*)crf_all, dim3(GRID), dim3(TB),
                                              args, 0, stream);
    if (e != hipSuccess){
        // discrete-launch fallback (same math, same buffers)
        k_init<<<dim3(NUPD), dim3(TB), 0, stream>>>(mask, du, q, S);
        for (int it = 0; it < NIT; ++it){
            k_phaseA<<<dim3(GRID), dim3(TB), 0, stream>>>(it, img, q, gH, pmsg, pksum);
            k_phaseB<<<dim3(NUPD), dim3(TB), 0, stream>>>(it, gH, pmsg, pksum, S, du, ksum, q, out);
        }
    }
}

// Round 4
// 196.627 us; speedup vs baseline: 6.3925x; 6.3925x over previous
//
#include <hip/hip_runtime.h>

constexpr int IMW  = 96;
constexpr int NPIX = 9216;
constexpr int TB   = 256;              // threads per block
constexpr int JT   = 4;                // j's per thread in bilat
constexpr int JB   = NPIX/(TB*JT);     // 9 j-blocks
constexpr int SI   = 192;              // i's per segment (2 image rows)
constexpr int NSEG = NPIX/SI;          // 48 segments
constexpr int NBIL = JB*NSEG;          // 432 bilat blocks
constexpr int NUPD = NPIX/TB;          // 36 update / gaussH blocks
constexpr int GRID = NBIL + NUPD;      // 468
constexpr int NIT  = 5;

constexpr float LCLIP = 18.420681f;               // -log(1e-8)
constexpr float LOG2E = 1.4426950408889634f;
constexpr float C1 = -LOG2E/18.0f;                // gaussian (sxy=3), base-2
constexpr float C2 = -LOG2E/5000.0f;              // bilateral spatial (sxy=50)
constexpr float C3 = -LOG2E/400.0f;               // bilateral feature (2*df^2/(2*20^2))

__global__ __launch_bounds__(TB) void k_init(const int* __restrict__ mask,
                                             float* __restrict__ du, float* __restrict__ q,
                                             float* __restrict__ S){
    int g = blockIdx.x*TB + threadIdx.x;
    if (g < NPIX){
        float d = (mask[g]==0) ? LCLIP : -LCLIP;
        du[g] = d;
        q[g]  = 1.0f/(1.0f + __expf(d));
    }
    if (g < IMW){
        float t = (float)g, acc = 0.f;
        for (int xp = 0; xp < IMW; ++xp){
            float dd = t - (float)xp;
            acc += exp2f(C1*dd*dd);
        }
        S[g] = acc;       // 1D gaussian row sum (for Ksum)
    }
}

// phaseA: 432 bilat blocks + 36 gaussH blocks in one grid
__global__ __launch_bounds__(TB) void k_phaseA(int iter, const float* __restrict__ img,
                                               const float* __restrict__ q,
                                               float* __restrict__ gH,
                                               float* __restrict__ pmsg,
                                               float* __restrict__ pksum){
    const int bid = blockIdx.x, tid = threadIdx.x;
    if (bid < NBIL){
        __shared__ float4 st[SI];
        const int jb  = bid / NSEG;
        const int seg = bid % NSEG;
        if (tid < SI){
            int i = seg*SI + tid;
            float fi = img[i];
            float xf = (float)(tid % IMW);
            // {f_i, u_i = C2*x^2 + C3*f^2, q_i, x}
            st[tid] = make_float4(fi, fmaf(C2*xf, xf, C3*fi*fi), q[i], xf);
        }
        float xj[JT], gx[JT], gf[JT], bb[JT], yj[JT];
        #pragma unroll
        for (int k = 0; k < JT; ++k){
            int j = jb*(TB*JT) + k*TB + tid;
            xj[k] = (float)(j % IMW);
            yj[k] = (float)(j / IMW);
            float fj = img[j];
            gx[k] = -2.0f*C2*xj[k];
            gf[k] = -2.0f*C3*fj;
            bb[k] = fmaf(C2*xj[k], xj[k], C3*fj*fj);   // C2*xj^2 + C3*fj^2
        }
        __syncthreads();

        float acc[JT] = {0,0,0,0}, ak[JT] = {0,0,0,0};
        const int r0 = seg*2;           // SI = 2 rows
        for (int r = 0; r < 2; ++r){
            float ry = (float)(r0 + r);
            float rc[JT];
            #pragma unroll
            for (int k = 0; k < JT; ++k){
                float dy = ry - yj[k];
                rc[k] = fmaf(C2*dy, dy, bb[k]);        // per (j,row) constant
            }
            if (iter == 0){
                #pragma unroll 4
                for (int x = 0; x < IMW; ++x){
                    float4 s = st[r*IMW + x];          // wave-uniform broadcast
                    #pragma unroll
                    for (int k = 0; k < JT; ++k){
                        float t = fmaf(s.x, gf[k], s.y + rc[k]);
                        float e = exp2f(fmaf(s.w, gx[k], t));
                        acc[k] = fmaf(s.z, e, acc[k]);
                        ak[k] += e;
                    }
                }
            } else {
                #pragma unroll 4
                for (int x = 0; x < IMW; ++x){
                    float4 s = st[r*IMW + x];
                    #pragma unroll
                    for (int k = 0; k < JT; ++k){
                        float t = fmaf(s.x, gf[k], s.y + rc[k]);
                        float e = exp2f(fmaf(s.w, gx[k], t));
                        acc[k] = fmaf(s.z, e, acc[k]);
                    }
                }
            }
        }
        #pragma unroll
        for (int k = 0; k < JT; ++k){
            int j = jb*(TB*JT) + k*TB + tid;
            pmsg[seg*NPIX + j] = acc[k];
            if (iter == 0) pksum[seg*NPIX + j] = ak[k];
        }
    } else {
        // separable gaussian, horizontal pass over fresh q
        int j  = (bid - NBIL)*TB + tid;
        int xjx = j % IMW, yjx = j / IMW;
        const float* row = q + yjx*IMW;
        float xjf = (float)xjx;
        float acc = 0.f;
        float dxf = -xjf;
        #pragma unroll 8
        for (int xp = 0; xp < IMW; ++xp){
            acc = fmaf(row[xp], exp2f(C1*dxf*dxf), acc);
            dxf += 1.f;
        }
        gH[j] = acc;
    }
}

// phaseB: vertical gaussian + partial reduce + mean-field update (36 blocks)
__global__ __launch_bounds__(TB) void k_phaseB(int iter,
                                               const float* __restrict__ gH,
                                               const float* __restrict__ pmsg,
                                               const float* __restrict__ pksum,
                                               const float* __restrict__ S,
                                               const float* __restrict__ du,
                                               float* __restrict__ ksum,
                                               float* __restrict__ q,
                                               float* __restrict__ out){
    int j  = blockIdx.x*TB + threadIdx.x;
    int xj = j % IMW, yj = j / IMW;
    float yjf = (float)yj;
    // vertical gaussian pass
    float gv = 0.f;
    float dyf = -yjf;
    #pragma unroll 8
    for (int yp = 0; yp < IMW; ++yp){
        gv = fmaf(gH[yp*IMW + xj], exp2f(C1*dyf*dyf), gv);
        dyf += 1.f;
    }
    // reduce bilateral partials (fixed order -> deterministic)
    float B = 0.f;
    #pragma unroll
    for (int s = 0; s < NSEG; ++s) B += pmsg[s*NPIX + j];
    float K;
    if (iter == 0){
        float Bk = 0.f;
        #pragma unroll
        for (int s = 0; s < NSEG; ++s) Bk += pksum[s*NPIX + j];
        K = 3.0f*S[xj]*S[yj] + 10.0f*Bk - 13.0f;    // remove diagonal (3+10)
        ksum[j] = K;
    } else {
        K = ksum[j];
    }
    float m = 3.0f*gv + 10.0f*B - 13.0f*q[j];        // remove diagonal q_j*K_jj
    float delta = du[j] + K - 2.0f*m;                // logit(1)-logit(0)
    if (iter == NIT-1){
        out[j] = (delta > 0.f) ? 1.0f : 0.0f;        // argmax; tie -> 0
    } else {
        q[j] = 1.0f/(1.0f + __expf(delta));
    }
}

extern "C" void kernel_launch(void* const* d_in, const int* in_sizes, int n_in,
                              void* d_out, int out_size, void* d_ws, size_t ws_size,
                              hipStream_t stream){
    const float* img  = (const float*)d_in[0];
    const int*   mask = (const int*)d_in[1];
    float* out = (float*)d_out;
    float* ws  = (float*)d_ws;

    float* q     = ws;
    float* du    = q    + NPIX;
    float* ksum  = du   + NPIX;
    float* gH    = ksum + NPIX;
    float* S     = gH   + NPIX;          // 96, pad to 128
    float* pmsg  = S    + 128;
    float* pksum = pmsg + (size_t)NSEG*NPIX;

    k_init<<<dim3(NUPD), dim3(TB), 0, stream>>>(mask, du, q, S);
    for (int it = 0; it < NIT; ++it){
        k_phaseA<<<dim3(GRID), dim3(TB), 0, stream>>>(it, img, q, gH, pmsg, pksum);
        k_phaseB<<<dim3(NUPD), dim3(TB), 0, stream>>>(it, gH, pmsg, pksum, S, du, ksum, q, out);
    }
}